// Round 11
// baseline (286.837 us; speedup 1.0000x reference)
//
#include <hip/hip_runtime.h>
#include <hip/hip_bf16.h>
#include <cstdint>

// DistanceAwareSelfAttention: SLEN=1024, BSZ=8, H=16, D=64, EMB=1024, CLIP=10
// Pipeline: f2b3 convert -> GEMM1 (in_proj, scatter to (3,b,h,s,d)) -> vtrans
//           -> qk band-bias -> flash attention -> GEMM2 (out_proj)
// R11: attn rebuilt on mfma_f32_32x32x16_bf16 — each wave covers 32 q-rows
//      (256/block, 512 blocks): LDS fragment traffic per q-row HALVED (was the
//      bottleneck: ~2048 cyc/CU/tile vs 1240 MFMA).  P repacked for PV via
//      pk2 + 2x shfl_xor(32) per k-step (C-layout reg-block 4 vs frag k-block 8).
//      8B-chunk swizzle swz(row)=(row^(row>>3))&7 (staging + reads) to keep
//      32-row b128 reads 2-way (free).  GEMMs/f2b3/vtrans/qkbias = R10.

typedef __attribute__((ext_vector_type(8))) __bf16 bf16x8;
typedef __attribute__((ext_vector_type(4))) __bf16 bf16x4;
typedef __attribute__((ext_vector_type(4))) float f32x4;
typedef __attribute__((ext_vector_type(16))) float f32x16;
typedef __attribute__((ext_vector_type(4))) unsigned u32x4;

#if __has_builtin(__builtin_amdgcn_exp2f)
#define EXP2F(x) __builtin_amdgcn_exp2f(x)
#else
#define EXP2F(x) exp2f(x)
#endif

#define MFMA32(A, B, C) __builtin_amdgcn_mfma_f32_32x32x16_bf16(A, B, C, 0, 0, 0)

__device__ __forceinline__ unsigned pk2(float lo, float hi) {
  unsigned short a = __builtin_bit_cast(unsigned short, (__bf16)lo);
  unsigned short b = __builtin_bit_cast(unsigned short, (__bf16)hi);
  return ((unsigned)b << 16) | a;
}

__device__ __forceinline__ void gload_lds16(const void* g, void* l) {
  __builtin_amdgcn_global_load_lds(
      (const __attribute__((address_space(1))) void*)g,
      (__attribute__((address_space(3))) void*)l, 16, 0, 0);
}

// one launch converting all three fp32 inputs to bf16
__global__ __launch_bounds__(256) void f2b3_kernel(
    const float* __restrict__ s0, __bf16* __restrict__ d0,
    const float* __restrict__ s1, __bf16* __restrict__ d1,
    const float* __restrict__ s2, __bf16* __restrict__ d2) {
  int i = (blockIdx.x * 256 + threadIdx.x) * 8;
  const float* s; __bf16* d; int off;
  if (i < 8388608) { s = s0; d = d0; off = i; }
  else if (i < 11534336) { s = s1; d = d1; off = i - 8388608; }
  else { s = s2; d = d2; off = i - 11534336; }
  float4 a = *(const float4*)(s + off);
  float4 b = *(const float4*)(s + off + 4);
  bf16x8 o;
  o[0] = (__bf16)a.x; o[1] = (__bf16)a.y; o[2] = (__bf16)a.z; o[3] = (__bf16)a.w;
  o[4] = (__bf16)b.x; o[5] = (__bf16)b.y; o[6] = (__bf16)b.z; o[7] = (__bf16)b.w;
  *(bf16x8*)(d + off) = o;
}

// C[m][n] = sum_k A[m][k]*B[n][k] + bias[n].  128x128 tile, BK=64, 4 waves.
// 1D grid with XCD-chunked bijective swizzle; NT = N/128 tiles per M-row band.
// EPI 0: scatter bf16 to qkvt (3,b,h,s,d), q scaled by 0.125*log2e.  EPI 1: fp32.
template <int EPI>
__global__ __launch_bounds__(256) void gemm_nt(
    const __bf16* __restrict__ A, const __bf16* __restrict__ B,
    const float* __restrict__ bias, int K,
    float* __restrict__ outF, __bf16* __restrict__ outT, int N, int NT, int CPX) {
  __shared__ __align__(16) __bf16 sA[128 * 64];
  __shared__ __align__(16) __bf16 sB[128 * 64];
  const int tid = threadIdx.x;
  const int wave = tid >> 6, lane = tid & 63;
  const int lg = lane >> 4, lr = lane & 15;
  const int wr = wave >> 1, wc = wave & 1;
  const int lid = (blockIdx.x & 7) * CPX + (blockIdx.x >> 3);
  const int m0 = (lid / NT) * 128;
  const int n0 = (lid % NT) * 128;

  f32x4 acc[4][4] = {};

  for (int kt = 0; kt < K; kt += 64) {
#pragma unroll
    for (int it = 0; it < 4; ++it) {
      int c = it * 256 + tid;
      int r = c >> 3, c8 = (c & 7) * 8;
      gload_lds16(A + (size_t)(m0 + r) * K + kt + c8,
                  (void*)&sA[(it * 256 + wave * 64) * 8]);
      gload_lds16(B + (size_t)(n0 + r) * K + kt + c8,
                  (void*)&sB[(it * 256 + wave * 64) * 8]);
    }
    __syncthreads();
#pragma unroll
    for (int kk = 0; kk < 2; ++kk) {
      bf16x8 af[4], bfr[4];
#pragma unroll
      for (int i = 0; i < 4; ++i)
        af[i] = *(const bf16x8*)&sA[(wr * 64 + i * 16 + lr) * 64 + kk * 32 + lg * 8];
#pragma unroll
      for (int j = 0; j < 4; ++j)
        bfr[j] = *(const bf16x8*)&sB[(wc * 64 + j * 16 + lr) * 64 + kk * 32 + lg * 8];
#pragma unroll
      for (int i = 0; i < 4; ++i)
#pragma unroll
        for (int j = 0; j < 4; ++j)
          acc[i][j] = __builtin_amdgcn_mfma_f32_16x16x32_bf16(af[i], bfr[j], acc[i][j], 0, 0, 0);
    }
    __syncthreads();
  }

#pragma unroll
  for (int i = 0; i < 4; ++i) {
    const int gm0 = m0 + wr * 64 + i * 16 + lg * 4;
#pragma unroll
    for (int j = 0; j < 4; ++j) {
      const int gn = n0 + wc * 64 + j * 16 + lr;
      const float bv = bias[gn];
#pragma unroll
      for (int rg = 0; rg < 4; ++rg) {
        const int gm = gm0 + rg;
        float v = acc[i][j][rg] + bv;
        if constexpr (EPI == 0) {
          int t = gn >> 10, h = (gn >> 6) & 15, d = gn & 63;
          int s = gm >> 3, b = gm & 7;
          if (t == 0) v *= 0.18033688011112042f;  // d^-0.5 * log2(e)
          outT[(((size_t)((t * 8 + b) * 16 + h) * 1024 + s) << 6) + d] = (__bf16)v;
        } else {
          outF[(size_t)gm * N + gn] = v;
        }
      }
    }
  }
}

// v (bh,s,d) -> vt (bh,d,s), 64x64 tiles
__global__ __launch_bounds__(256) void vtrans_kernel(const __bf16* __restrict__ v,
                                                     __bf16* __restrict__ vt) {
  __shared__ __bf16 tile[64][66];
  const int tid = threadIdx.x;
  const int bh = blockIdx.x >> 4;
  const int s0 = (blockIdx.x & 15) * 64;
  const __bf16* src = v + ((size_t)bh * 1024 + s0) * 64;
#pragma unroll
  for (int it = 0; it < 4; ++it) {
    int idx = it * 256 + tid;
    int r = idx >> 4, c4 = (idx & 15) * 4;
    bf16x4 x = *(const bf16x4*)&src[r * 64 + c4];
    tile[r][c4 + 0] = x[0]; tile[r][c4 + 1] = x[1];
    tile[r][c4 + 2] = x[2]; tile[r][c4 + 3] = x[3];
  }
  __syncthreads();
  __bf16* dst = vt + (size_t)bh * 65536;
#pragma unroll
  for (int it = 0; it < 4; ++it) {
    int idx = it * 256 + tid;
    int dr = idx >> 4, s4 = (idx & 15) * 4;
    bf16x4 y;
    y[0] = tile[s4 + 0][dr]; y[1] = tile[s4 + 1][dr];
    y[2] = tile[s4 + 2][dr]; y[3] = tile[s4 + 3][dr];
    *(bf16x4*)&dst[(size_t)dr * 1024 + s0 + s4] = y;
  }
}

// biasD[row][c] = q[row]·(kde[c]-kde[10]) for c<10, else 0.  row = bh*1024+s.
__global__ __launch_bounds__(256) void qkbias_kernel(const __bf16* __restrict__ q,
                                                     const float* __restrict__ kde,
                                                     float* __restrict__ biasD) {
  const int row = blockIdx.x * 16 + (threadIdx.x >> 4);
  const int c = threadIdx.x & 15;
  float acc = 0.f;
  if (c < 10) {
    const bf16x8* qr = (const bf16x8*)(q + (size_t)row * 64);
#pragma unroll
    for (int d8 = 0; d8 < 8; ++d8) {
      bf16x8 qv = qr[d8];
#pragma unroll
      for (int j = 0; j < 8; ++j)
        acc += (float)qv[j] * (kde[c * 64 + d8 * 8 + j] - kde[640 + d8 * 8 + j]);
    }
  }
  biasD[(size_t)row * 16 + c] = acc;
}

// ---- PV k-step (KS literal 0..3): build P B-frag (k = tloc = 8*hb + j) from
// S^T C-layout regs (tloc = (i&3)+8*(i>>2)+4*hb), then 2 MFMAs (dtile 0,1).
#define PV_KS(ZZ, KS)                                                           \
  {                                                                             \
    unsigned w0 = pk2(ZZ[8 * ((KS) & 1) + 0], ZZ[8 * ((KS) & 1) + 1]);          \
    unsigned w1 = pk2(ZZ[8 * ((KS) & 1) + 2], ZZ[8 * ((KS) & 1) + 3]);          \
    unsigned w2 = pk2(ZZ[8 * ((KS) & 1) + 4], ZZ[8 * ((KS) & 1) + 5]);          \
    unsigned w3 = pk2(ZZ[8 * ((KS) & 1) + 6], ZZ[8 * ((KS) & 1) + 7]);          \
    unsigned e1 = hb ? w0 : w2, e2 = hb ? w1 : w3;                              \
    unsigned r1 = (unsigned)__shfl_xor((int)e1, 32, 64);                        \
    unsigned r2 = (unsigned)__shfl_xor((int)e2, 32, 64);                        \
    u32x4 bw = {hb ? r1 : w0, hb ? r2 : w1, hb ? w2 : r1, hb ? w3 : r2};        \
    bf16x8 pb = __builtin_bit_cast(bf16x8, bw);                                 \
    bf16x8 a0 = *(const bf16x8*)&vb[l31 * 64 + (((2 * (KS) + hb) ^ swz0) * 8)]; \
    bf16x8 a1 = *(const bf16x8*)&vb[(32 + l31) * 64 + (((2 * (KS) + hb) ^ swz0 ^ 4) * 8)]; \
    o0 = MFMA32(a0, pb, o0);                                                    \
    o1 = MFMA32(a1, pb, o1);                                                    \
  }

// ---- attn per-tile macro: KT/BC/BS LITERAL.
#define ATTN_TILE(KT, BC, BS)                                                   \
  {                                                                             \
    if ((KT) < 14) {                                                            \
      gload_lds16(kp + (size_t)((KT) * 64 + 128 + srow) * 64 + sc8,             \
                  &sK[BS][wave * 512]);                                         \
      gload_lds16(vtp + (size_t)srow * 1024 + (KT) * 64 + 128 + sc8,            \
                  &sV[BS][wave * 512]);                                         \
    }                                                                           \
    const __bf16* kb = sK[BC];                                                  \
    const __bf16* vb = sV[BC];                                                  \
    f32x16 z0 = {}, z1 = {};                                                    \
    __builtin_amdgcn_s_setprio(1);                                              \
    _Pragma("unroll") for (int kk = 0; kk < 4; ++kk) {                          \
      bf16x8 k0 = *(const bf16x8*)&kb[l31 * 64 + (((2 * kk + hb) ^ swz0) * 8)]; \
      bf16x8 k1 = *(const bf16x8*)&kb[(32 + l31) * 64 + (((2 * kk + hb) ^ swz0 ^ 4) * 8)]; \
      z0 = MFMA32(k0, aq[kk], z0);                                              \
      z1 = MFMA32(k1, aq[kk], z1);                                              \
    }                                                                           \
    __builtin_amdgcn_s_setprio(0);                                              \
    const bool inband = ((KT) * 64 <= sb + 40) && ((KT) * 64 + 63 >= sb - 9);   \
    if (inband) {                                                               \
      const float* bDrow = biasD + ((size_t)bh * 1024 + s) * 16;                \
      _Pragma("unroll") for (int rr = 0; rr < 16; ++rr) {                       \
        {                                                                       \
          const int t = (KT) * 64 + (rr & 3) + 8 * (rr >> 2) + 4 * hb;          \
          const int dd = t - s;                                                 \
          const int ad = dd < 0 ? -dd : dd;                                     \
          const int c = ad < 15 ? ad : 15;                                      \
          const float val = z0[rr] + bDrow[c];                                  \
          z0[rr] = val;                                                         \
          if (ad <= 9) band[wave][l31][dd + 9] = val;                           \
        }                                                                       \
        {                                                                       \
          const int t = (KT) * 64 + 32 + (rr & 3) + 8 * (rr >> 2) + 4 * hb;     \
          const int dd = t - s;                                                 \
          const int ad = dd < 0 ? -dd : dd;                                     \
          const int c = ad < 15 ? ad : 15;                                      \
          const float val = z1[rr] + bDrow[c];                                  \
          z1[rr] = val;                                                         \
          if (ad <= 9) band[wave][l31][dd + 9] = val;                           \
        }                                                                       \
      }                                                                         \
    }                                                                           \
    float vmax = fmaxf(z0[0], z1[0]);                                           \
    _Pragma("unroll") for (int rr = 1; rr < 16; ++rr)                           \
      vmax = fmaxf(vmax, fmaxf(z0[rr], z1[rr]));                                \
    vmax = fmaxf(vmax, __shfl_xor(vmax, 32, 64));                               \
    if (__any(vmax > m + 8.f)) {                                                \
      const float mn = fmaxf(m, vmax);                                          \
      const float scl = EXP2F(m - mn);                                          \
      m = mn;                                                                   \
      l *= scl;                                                                 \
      _Pragma("unroll") for (int rr = 0; rr < 16; ++rr) {                       \
        o0[rr] *= scl;                                                          \
        o1[rr] *= scl;                                                          \
      }                                                                         \
    }                                                                           \
    float rsum = 0.f;                                                           \
    _Pragma("unroll") for (int rr = 0; rr < 16; ++rr) {                         \
      float p0 = EXP2F(z0[rr] - m), p1 = EXP2F(z1[rr] - m);                     \
      z0[rr] = p0; z1[rr] = p1;                                                 \
      rsum += p0 + p1;                                                          \
    }                                                                           \
    rsum += __shfl_xor(rsum, 32, 64);                                           \
    l += rsum;                                                                  \
    __builtin_amdgcn_s_setprio(1);                                              \
    PV_KS(z0, 0)                                                                \
    PV_KS(z0, 1)                                                                \
    PV_KS(z1, 2)                                                                \
    PV_KS(z1, 3)                                                                \
    __builtin_amdgcn_s_setprio(0);                                              \
  }

#define ATTN_W2 asm volatile("s_waitcnt vmcnt(2)" ::: "memory"); __builtin_amdgcn_s_barrier();
#define ATTN_W0 asm volatile("s_waitcnt vmcnt(0)" ::: "memory"); __builtin_amdgcn_s_barrier();

// Flash attention w/ distance band.  8 waves x 32 q-rows (Q-block 256), KV tiles 64.
// Swapped QK^T on 32x32x16 (S^T: row=t=(reg&3)+8(reg>>2)+4hb, col=q=lane&31);
// per-lane softmax (1 shfl); PV on 32x32x16 with pk2+shfl P repack; O^T accum.
__global__ __launch_bounds__(512) void attn_kernel(
    const __bf16* __restrict__ qkv, const __bf16* __restrict__ vt,
    const float* __restrict__ biasD, const float* __restrict__ vde,
    __bf16* __restrict__ O) {
  __shared__ __align__(16) __bf16 sK[3][4096];   // [64 t][64 k], 8B-chunk swz swizzled
  __shared__ __align__(16) __bf16 sV[3][4096];   // [64 d][64 t], 8B-chunk swz swizzled
  __shared__ float band[8][32][20];              // band logits (log2 dom), slot=(t-s)+9
  const int tid = threadIdx.x, wave = tid >> 6, lane = tid & 63;
  const int l31 = lane & 31, hb = lane >> 5;
  // XCD-chunked bijective swizzle: 512 blocks -> 8 chunks of 64; the 4 stile
  // blocks of a bh stay on one XCD.
  const int lid = (blockIdx.x & 7) * 64 + (blockIdx.x >> 3);
  const int bh = lid >> 2;
  const int stile = lid & 3;
  const int sb = stile * 256 + wave * 32;
  const int b = bh >> 4, h = bh & 15;
  const __bf16* qp = qkv + (size_t)bh * 65536;
  const __bf16* kp = qkv + (size_t)(128 + bh) * 65536;
  const __bf16* vtp = vt + (size_t)bh * 65536;

  // fragment-read swizzle base for this lane (row = l31 / 32+l31)
  const int swz0 = (l31 ^ (l31 >> 3)) & 7;

  // staging: 512 threads cover one 64x64 tile; row=tid>>3, chunk=tid&7, source
  // chunk XOR'd by swz(row) (gload_lds dest linear, rule #21).
  const int srow = tid >> 3;
  const int sc8 = ((tid & 7) ^ ((srow ^ (srow >> 3)) & 7)) * 8;

  // prologue: stage tiles 0,1
  gload_lds16(kp + (size_t)srow * 64 + sc8, &sK[0][wave * 512]);
  gload_lds16(vtp + (size_t)srow * 1024 + sc8, &sV[0][wave * 512]);
  gload_lds16(kp + (size_t)(64 + srow) * 64 + sc8, &sK[1][wave * 512]);
  gload_lds16(vtp + (size_t)srow * 1024 + 64 + sc8, &sV[1][wave * 512]);

  {
    float* bf = &band[0][0][0];
    for (int i = tid; i < 8 * 32 * 20; i += 512) bf[i] = -1e30f;
  }

  // Q B-frags: q = sb + l31, k-step kk: d = 16*kk + 8*hb + j
  bf16x8 aq[4];
#pragma unroll
  for (int kk = 0; kk < 4; ++kk)
    aq[kk] = *(const bf16x8*)&qp[(size_t)(sb + l31) * 64 + kk * 16 + hb * 8];

  f32x16 o0 = {}, o1 = {};  // O^T: d = dtile*32 + (reg&3)+8*(reg>>2)+4*hb, q = l31
  float m = -1e30f, l = 0.f;
  const int s = sb + l31;  // this lane's q row (hb=0,1 lanes duplicate q)

  ATTN_W2                    // tile0 staged; tile1's 2 ops may be outstanding
  ATTN_TILE(0, 0, 2)  ATTN_W2
  ATTN_TILE(1, 1, 0)  ATTN_W2
  ATTN_TILE(2, 2, 1)  ATTN_W2
  ATTN_TILE(3, 0, 2)  ATTN_W2
  ATTN_TILE(4, 1, 0)  ATTN_W2
  ATTN_TILE(5, 2, 1)  ATTN_W2
  ATTN_TILE(6, 0, 2)  ATTN_W2
  ATTN_TILE(7, 1, 0)  ATTN_W2
  ATTN_TILE(8, 2, 1)  ATTN_W2
  ATTN_TILE(9, 0, 2)  ATTN_W2
  ATTN_TILE(10, 1, 0) ATTN_W2
  ATTN_TILE(11, 2, 1) ATTN_W2
  ATTN_TILE(12, 0, 2) ATTN_W2
  ATTN_TILE(13, 1, 0) ATTN_W0
  ATTN_TILE(14, 2, 1) ATTN_W0
  ATTN_TILE(15, 0, 2)

  // ---- epilogue: normalize + v_dist band correction, write (s,b,h*d) bf16 ----
  const float inv = 1.f / l;
  float psum[10];
  psum[0] = EXP2F(band[wave][l31][9] - m);
#pragma unroll
  for (int c = 1; c < 10; ++c)
    psum[c] = EXP2F(band[wave][l31][9 - c] - m) +
              EXP2F(band[wave][l31][9 + c] - m);
#pragma unroll
  for (int g = 0; g < 4; ++g) {
    bf16x4 ov0, ov1;
#pragma unroll
    for (int rg = 0; rg < 4; ++rg) {
      {
        const int d = 8 * g + 4 * hb + rg;
        float acc2 = 0.f;
#pragma unroll
        for (int c = 0; c < 10; ++c)
          acc2 += psum[c] * (vde[c * 64 + d] - vde[640 + d]);
        ov0[rg] = (__bf16)((o0[4 * g + rg] + acc2) * inv + vde[640 + d]);
      }
      {
        const int d = 32 + 8 * g + 4 * hb + rg;
        float acc2 = 0.f;
#pragma unroll
        for (int c = 0; c < 10; ++c)
          acc2 += psum[c] * (vde[c * 64 + d] - vde[640 + d]);
        ov1[rg] = (__bf16)((o1[4 * g + rg] + acc2) * inv + vde[640 + d]);
      }
    }
    __bf16* orow = O + ((size_t)(s * 8 + b)) * 1024 + h * 64;
    *(bf16x4*)&orow[8 * g + 4 * hb] = ov0;
    *(bf16x4*)&orow[32 + 8 * g + 4 * hb] = ov1;
  }
}

extern "C" void kernel_launch(void* const* d_in, const int* in_sizes, int n_in,
                              void* d_out, int out_size, void* d_ws, size_t ws_size,
                              hipStream_t stream) {
  (void)in_sizes; (void)n_in; (void)out_size; (void)ws_size;
  const float* inputs = (const float*)d_in[0];
  const float* W_in   = (const float*)d_in[1];
  const float* b_in   = (const float*)d_in[2];
  const float* kde    = (const float*)d_in[3];
  const float* vde    = (const float*)d_in[4];
  const float* W_out  = (const float*)d_in[5];
  const float* b_out  = (const float*)d_in[6];
  float* out = (float*)d_out;

  char* ws = (char*)d_ws;
  __bf16* qkvt  = (__bf16*)(ws);              // (3,8,16,1024,64) bf16: 50331648 B
  __bf16* vt    = (__bf16*)(ws + 50331648);   // (128,64,1024)  bf16: 16777216 B
  float*  biasD = (float*) (ws + 67108864);   // (131072,16)    f32:   8388608 B
  __bf16* Xb    = (__bf16*)(ws + 75497472);   // (8192,1024)    bf16: 16777216 B
  __bf16* Ob    = (__bf16*)(ws + 75497472);   // reuse Xb region after GEMM1
  __bf16* Wb_in = (__bf16*)(ws + 92274688);   // (3072,1024)    bf16:  6291456 B
  __bf16* Wb_out= (__bf16*)(ws + 98566144);   // (1024,1024)    bf16:  2097152 B

  f2b3_kernel<<<6144, 256, 0, stream>>>(inputs, Xb, W_in, Wb_in, W_out, Wb_out);

  // GEMM1: 64 M-bands x 24 N-tiles = 1536 blocks (1536 % 8 == 0, CPX=192)
  gemm_nt<0><<<1536, 256, 0, stream>>>(Xb, Wb_in, b_in, 1024, nullptr, qkvt, 3072, 24, 192);
  vtrans_kernel<<<2048, 256, 0, stream>>>(qkvt + (size_t)2 * 128 * 65536, vt);
  qkbias_kernel<<<8192, 256, 0, stream>>>(qkvt, kde, biasD);
  attn_kernel<<<512, 512, 0, stream>>>(qkvt, vt, biasD, vde, Ob);
  // GEMM2: 64 x 8 = 512 blocks (CPX=64)
  gemm_nt<1><<<512, 256, 0, stream>>>(Ob, Wb_out, b_out, 1024, out, nullptr, 1024, 8, 64);
}

// Round 12
// 252.457 us; speedup vs baseline: 1.1362x; 1.1362x over previous
//
#include <hip/hip_runtime.h>
#include <hip/hip_bf16.h>
#include <cstdint>

// DistanceAwareSelfAttention: SLEN=1024, BSZ=8, H=16, D=64, EMB=1024, CLIP=10
// Pipeline: f2b3 convert -> GEMM1 (in_proj, scatter to (3,b,h,s,d)) -> vtrans
//           -> qk band-bias -> flash attention -> GEMM2 (out_proj)
// R12: attn reverted to R10's known-good 16x16 kernel (R11's 32x32 lengthened the
//      per-wave serial chain and halved occupancy).  GEMMs: double-buffered LDS +
//      counted s_waitcnt vmcnt(8) + raw s_barrier (T3-minimum 2-phase) — stage(t+1)
//      issued BEFORE compute(t); no more full vmcnt(0) drain per K-step.

typedef __attribute__((ext_vector_type(8))) __bf16 bf16x8;
typedef __attribute__((ext_vector_type(4))) __bf16 bf16x4;
typedef __attribute__((ext_vector_type(4))) short s16x4;
typedef __attribute__((ext_vector_type(4))) float f32x4;

#if __has_builtin(__builtin_amdgcn_exp2f)
#define EXP2F(x) __builtin_amdgcn_exp2f(x)
#else
#define EXP2F(x) exp2f(x)
#endif

#if __has_builtin(__builtin_amdgcn_mfma_f32_16x16x16bf16_1k)
#define PV_MFMA(ACC, AV, BV) \
  ACC = __builtin_amdgcn_mfma_f32_16x16x16bf16_1k( \
      __builtin_bit_cast(s16x4, AV), __builtin_bit_cast(s16x4, BV), ACC, 0, 0, 0)
#elif __has_builtin(__builtin_amdgcn_mfma_f32_16x16x16_bf16)
#define PV_MFMA(ACC, AV, BV) \
  ACC = __builtin_amdgcn_mfma_f32_16x16x16_bf16(AV, BV, ACC, 0, 0, 0)
#else
#define PV_MFMA(ACC, AV, BV)                                               \
  asm volatile("s_nop 1\n\tv_mfma_f32_16x16x16_bf16 %0, %1, %2, %0\n\t"    \
               "s_nop 7\n\ts_nop 7"                                        \
               : "+v"(ACC)                                                 \
               : "v"(__builtin_bit_cast(s16x4, AV)),                       \
                 "v"(__builtin_bit_cast(s16x4, BV)))
#endif

__device__ __forceinline__ void gload_lds16(const void* g, void* l) {
  __builtin_amdgcn_global_load_lds(
      (const __attribute__((address_space(1))) void*)g,
      (__attribute__((address_space(3))) void*)l, 16, 0, 0);
}

// one launch converting all three fp32 inputs to bf16
__global__ __launch_bounds__(256) void f2b3_kernel(
    const float* __restrict__ s0, __bf16* __restrict__ d0,
    const float* __restrict__ s1, __bf16* __restrict__ d1,
    const float* __restrict__ s2, __bf16* __restrict__ d2) {
  int i = (blockIdx.x * 256 + threadIdx.x) * 8;
  const float* s; __bf16* d; int off;
  if (i < 8388608) { s = s0; d = d0; off = i; }
  else if (i < 11534336) { s = s1; d = d1; off = i - 8388608; }
  else { s = s2; d = d2; off = i - 11534336; }
  float4 a = *(const float4*)(s + off);
  float4 b = *(const float4*)(s + off + 4);
  bf16x8 o;
  o[0] = (__bf16)a.x; o[1] = (__bf16)a.y; o[2] = (__bf16)a.z; o[3] = (__bf16)a.w;
  o[4] = (__bf16)b.x; o[5] = (__bf16)b.y; o[6] = (__bf16)b.z; o[7] = (__bf16)b.w;
  *(bf16x8*)(d + off) = o;
}

// C[m][n] = sum_k A[m][k]*B[n][k] + bias[n].  128x128 tile, BK=64, 4 waves.
// Double-buffered LDS, counted vmcnt(8): stage(t+1) in flight across compute(t).
// 1D grid with XCD-chunked bijective swizzle; NT = N/128 tiles per M-row band.
// EPI 0: scatter bf16 to qkvt (3,b,h,s,d), q scaled by 0.125*log2e.  EPI 1: fp32.
template <int EPI>
__global__ __launch_bounds__(256) void gemm_nt(
    const __bf16* __restrict__ A, const __bf16* __restrict__ B,
    const float* __restrict__ bias, int K,
    float* __restrict__ outF, __bf16* __restrict__ outT, int N, int NT, int CPX) {
  __shared__ __align__(16) __bf16 sA[2][128 * 64];
  __shared__ __align__(16) __bf16 sB[2][128 * 64];
  const int tid = threadIdx.x;
  const int wave = tid >> 6, lane = tid & 63;
  const int lg = lane >> 4, lr = lane & 15;
  const int wr = wave >> 1, wc = wave & 1;
  const int lid = (blockIdx.x & 7) * CPX + (blockIdx.x >> 3);
  const int m0 = (lid / NT) * 128;
  const int n0 = (lid % NT) * 128;

  const int sr = tid >> 3;            // staged row 0..127 (wave-contig blocks of 8)
  const int sc8 = (tid & 7) * 8;      // 16B chunk within row

#define GSTAGE(BUF, KT)                                                     \
  _Pragma("unroll") for (int it = 0; it < 4; ++it) {                        \
    int r = (it << 5) + sr % 32 + (sr / 32) * 0;                            \
    (void)r;                                                                \
  }

  f32x4 acc[4][4] = {};

  // stage tile kt into sA/sB[BUF]: 4 A-ops + 4 B-ops per thread (8 total).
  // thread covers rows tid>>3 + it*32?  Keep original mapping: c = it*256+tid.
#define STAGE_G(BUF, KT)                                                    \
  _Pragma("unroll") for (int it = 0; it < 4; ++it) {                        \
    int c = it * 256 + tid;                                                 \
    int r = c >> 3, c8 = (c & 7) * 8;                                       \
    gload_lds16(A + (size_t)(m0 + r) * K + (KT) + c8,                       \
                (void*)&sA[BUF][(it * 256 + wave * 64) * 8]);               \
    gload_lds16(B + (size_t)(n0 + r) * K + (KT) + c8,                       \
                (void*)&sB[BUF][(it * 256 + wave * 64) * 8]);               \
  }

  STAGE_G(0, 0)
  int buf = 0;
  for (int kt = 0; kt < K; kt += 64) {
    if (kt + 64 < K) {
      STAGE_G(buf ^ 1, kt + 64)
      asm volatile("s_waitcnt vmcnt(8)" ::: "memory");  // tile t staged; t+1 in flight
    } else {
      asm volatile("s_waitcnt vmcnt(0)" ::: "memory");
    }
    __builtin_amdgcn_s_barrier();
#pragma unroll
    for (int kk = 0; kk < 2; ++kk) {
      bf16x8 af[4], bfr[4];
#pragma unroll
      for (int i = 0; i < 4; ++i)
        af[i] = *(const bf16x8*)&sA[buf][(wr * 64 + i * 16 + lr) * 64 + kk * 32 + lg * 8];
#pragma unroll
      for (int j = 0; j < 4; ++j)
        bfr[j] = *(const bf16x8*)&sB[buf][(wc * 64 + j * 16 + lr) * 64 + kk * 32 + lg * 8];
#pragma unroll
      for (int i = 0; i < 4; ++i)
#pragma unroll
        for (int j = 0; j < 4; ++j)
          acc[i][j] = __builtin_amdgcn_mfma_f32_16x16x32_bf16(af[i], bfr[j], acc[i][j], 0, 0, 0);
    }
    __builtin_amdgcn_s_barrier();  // all waves done reading buf before overwrite
    buf ^= 1;
  }

#pragma unroll
  for (int i = 0; i < 4; ++i) {
    const int gm0 = m0 + wr * 64 + i * 16 + lg * 4;
#pragma unroll
    for (int j = 0; j < 4; ++j) {
      const int gn = n0 + wc * 64 + j * 16 + lr;
      const float bv = bias[gn];
#pragma unroll
      for (int rg = 0; rg < 4; ++rg) {
        const int gm = gm0 + rg;
        float v = acc[i][j][rg] + bv;
        if constexpr (EPI == 0) {
          int t = gn >> 10, h = (gn >> 6) & 15, d = gn & 63;
          int s = gm >> 3, b = gm & 7;
          if (t == 0) v *= 0.18033688011112042f;  // d^-0.5 * log2(e)
          outT[(((size_t)((t * 8 + b) * 16 + h) * 1024 + s) << 6) + d] = (__bf16)v;
        } else {
          outF[(size_t)gm * N + gn] = v;
        }
      }
    }
  }
#undef STAGE_G
#undef GSTAGE
}

// v (bh,s,d) -> vt (bh,d,s), 64x64 tiles
__global__ __launch_bounds__(256) void vtrans_kernel(const __bf16* __restrict__ v,
                                                     __bf16* __restrict__ vt) {
  __shared__ __bf16 tile[64][66];
  const int tid = threadIdx.x;
  const int bh = blockIdx.x >> 4;
  const int s0 = (blockIdx.x & 15) * 64;
  const __bf16* src = v + ((size_t)bh * 1024 + s0) * 64;
#pragma unroll
  for (int it = 0; it < 4; ++it) {
    int idx = it * 256 + tid;
    int r = idx >> 4, c4 = (idx & 15) * 4;
    bf16x4 x = *(const bf16x4*)&src[r * 64 + c4];
    tile[r][c4 + 0] = x[0]; tile[r][c4 + 1] = x[1];
    tile[r][c4 + 2] = x[2]; tile[r][c4 + 3] = x[3];
  }
  __syncthreads();
  __bf16* dst = vt + (size_t)bh * 65536;
#pragma unroll
  for (int it = 0; it < 4; ++it) {
    int idx = it * 256 + tid;
    int dr = idx >> 4, s4 = (idx & 15) * 4;
    bf16x4 y;
    y[0] = tile[s4 + 0][dr]; y[1] = tile[s4 + 1][dr];
    y[2] = tile[s4 + 2][dr]; y[3] = tile[s4 + 3][dr];
    *(bf16x4*)&dst[(size_t)dr * 1024 + s0 + s4] = y;
  }
}

// biasD[row][c] = q[row]·(kde[c]-kde[10]) for c<10, else 0.  row = bh*1024+s.
__global__ __launch_bounds__(256) void qkbias_kernel(const __bf16* __restrict__ q,
                                                     const float* __restrict__ kde,
                                                     float* __restrict__ biasD) {
  const int row = blockIdx.x * 16 + (threadIdx.x >> 4);
  const int c = threadIdx.x & 15;
  float acc = 0.f;
  if (c < 10) {
    const bf16x8* qr = (const bf16x8*)(q + (size_t)row * 64);
#pragma unroll
    for (int d8 = 0; d8 < 8; ++d8) {
      bf16x8 qv = qr[d8];
#pragma unroll
      for (int j = 0; j < 8; ++j)
        acc += (float)qv[j] * (kde[c * 64 + d8 * 8 + j] - kde[640 + d8 * 8 + j]);
    }
  }
  biasD[(size_t)row * 16 + c] = acc;
}

// ---- attn per-tile macro: KT/BC/BS are LITERALS (addresses fold to vaddr+imm).
#define ATTN_TILE(KT, BC, BS)                                                   \
  {                                                                             \
    if ((KT) < 14) {                                                            \
      gload_lds16(kp + (size_t)((KT) * 64 + 128 + srow) * 64 + sc8,             \
                  &sK[BS][wave * 512]);                                         \
      gload_lds16(vtp + (size_t)srow * 1024 + (KT) * 64 + 128 + sc8,            \
                  &sV[BS][wave * 512]);                                         \
    }                                                                           \
    f32x4 sf[4];                                                                \
    __builtin_amdgcn_s_setprio(1);                                              \
    _Pragma("unroll") for (int tj = 0; tj < 4; ++tj) {                          \
      const int t = tj * 16 + lr;                                               \
      bf16x8 bk0 = *(const bf16x8*)&sK[BC][t * 64 + ((lg ^ (t & 7)) * 8)];      \
      bf16x8 bk1 = *(const bf16x8*)&sK[BC][t * 64 + (((4 + lg) ^ (t & 7)) * 8)];\
      f32x4 z = {};                                                             \
      z = __builtin_amdgcn_mfma_f32_16x16x32_bf16(bk0, aq[0], z, 0, 0, 0);      \
      z = __builtin_amdgcn_mfma_f32_16x16x32_bf16(bk1, aq[1], z, 0, 0, 0);      \
      sf[tj] = z;                                                               \
    }                                                                           \
    __builtin_amdgcn_s_setprio(0);                                              \
    const bool inband = ((KT) * 64 <= sb + 24) && ((KT) * 64 + 63 >= sb - 9);   \
    if (inband) {                                                               \
      const float* bDrow = biasD + ((size_t)bh * 1024 + s) * 16;                \
      _Pragma("unroll") for (int tj = 0; tj < 4; ++tj) {                        \
        _Pragma("unroll") for (int rg = 0; rg < 4; ++rg) {                      \
          const int t = (KT) * 64 + tj * 16 + lg * 4 + rg;                      \
          const int dd = t - s;                                                 \
          const int ad = dd < 0 ? -dd : dd;                                     \
          const int c = ad < 15 ? ad : 15;                                      \
          const float val = sf[tj][rg] + bDrow[c];                              \
          sf[tj][rg] = val;                                                     \
          if (ad <= 9) band[wave][lr][dd + 9] = val;                            \
        }                                                                       \
      }                                                                         \
    }                                                                           \
    float vm[4];                                                                \
    _Pragma("unroll") for (int tj = 0; tj < 4; ++tj)                            \
      vm[tj] = fmaxf(fmaxf(sf[tj][0], sf[tj][1]), fmaxf(sf[tj][2], sf[tj][3])); \
    float vmax = fmaxf(fmaxf(vm[0], vm[1]), fmaxf(vm[2], vm[3]));               \
    vmax = fmaxf(vmax, __shfl_xor(vmax, 16, 64));                               \
    vmax = fmaxf(vmax, __shfl_xor(vmax, 32, 64));                               \
    if (__any(vmax > m + 8.f)) {                                                \
      const float mn = fmaxf(m, vmax);                                          \
      const float scl = EXP2F(m - mn);                                          \
      m = mn;                                                                   \
      l *= scl;                                                                 \
      _Pragma("unroll") for (int dj = 0; dj < 4; ++dj)                          \
        _Pragma("unroll") for (int rg = 0; rg < 4; ++rg)                        \
          o_acc[dj][rg] *= scl;                                                 \
    }                                                                           \
    float rs[4];                                                                \
    _Pragma("unroll") for (int tj = 0; tj < 4; ++tj) {                          \
      float p0 = EXP2F(sf[tj][0] - m), p1 = EXP2F(sf[tj][1] - m);               \
      float p2 = EXP2F(sf[tj][2] - m), p3 = EXP2F(sf[tj][3] - m);               \
      sf[tj][0] = p0; sf[tj][1] = p1; sf[tj][2] = p2; sf[tj][3] = p3;           \
      rs[tj] = (p0 + p1) + (p2 + p3);                                           \
    }                                                                           \
    float rsum = (rs[0] + rs[1]) + (rs[2] + rs[3]);                             \
    rsum += __shfl_xor(rsum, 16, 64);                                           \
    rsum += __shfl_xor(rsum, 32, 64);                                           \
    l += rsum;                                                                  \
    bf16x4 pbv[4];                                                              \
    _Pragma("unroll") for (int tj = 0; tj < 4; ++tj) {                          \
      pbv[tj][0] = (__bf16)sf[tj][0]; pbv[tj][1] = (__bf16)sf[tj][1];           \
      pbv[tj][2] = (__bf16)sf[tj][2]; pbv[tj][3] = (__bf16)sf[tj][3];           \
    }                                                                           \
    __builtin_amdgcn_s_setprio(1);                                              \
    _Pragma("unroll") for (int tj = 0; tj < 4; ++tj) {                          \
      _Pragma("unroll") for (int dj = 0; dj < 4; ++dj) {                        \
        const int d = dj * 16 + lr;                                             \
        const int ch = (2 * tj + (lg >> 1)) ^ (d & 7);                          \
        const bf16x4 av = *(const bf16x4*)&sV[BC][d * 64 + ch * 8 + (lg & 1) * 4]; \
        PV_MFMA(o_acc[dj], av, pbv[tj]);                                        \
      }                                                                         \
    }                                                                           \
    __builtin_amdgcn_s_setprio(0);                                              \
  }

#define ATTN_W2 asm volatile("s_waitcnt vmcnt(2)" ::: "memory"); __builtin_amdgcn_s_barrier();
#define ATTN_W0 asm volatile("s_waitcnt vmcnt(0)" ::: "memory"); __builtin_amdgcn_s_barrier();

// Flash attention w/ distance band.  8 waves, 16 q-rows/wave, KV tiles of 64.
// Swapped QK^T, per-lane softmax, zero-shuffle PV via 16x16x16.  Triple-buffered
// K/V staging, counted vmcnt(2), fully unrolled.  NO min-waves bound.
__global__ __launch_bounds__(512) void attn_kernel(
    const __bf16* __restrict__ qkv, const __bf16* __restrict__ vt,
    const float* __restrict__ biasD, const float* __restrict__ vde,
    __bf16* __restrict__ O) {
  __shared__ __align__(16) __bf16 sK[3][4096];   // [64 t][64 k], 16B-chunk XOR swizzled
  __shared__ __align__(16) __bf16 sV[3][4096];   // [64 d][64 t], 16B-chunk XOR swizzled
  __shared__ float band[8][16][20];              // band logits (log2 dom), slot=(t-s)+9
  const int tid = threadIdx.x, wave = tid >> 6, lane = tid & 63;
  const int lg = lane >> 4, lr = lane & 15;
  const int lid = (blockIdx.x & 7) * 128 + (blockIdx.x >> 3);
  const int bh = lid >> 3;
  const int stile = lid & 7;
  const int sb = stile * 128 + wave * 16;
  const int b = bh >> 4, h = bh & 15;
  const __bf16* qp = qkv + (size_t)bh * 65536;
  const __bf16* kp = qkv + (size_t)(128 + bh) * 65536;
  const __bf16* vtp = vt + (size_t)bh * 65536;

  const int srow = tid >> 3;
  const int sc8 = ((tid & 7) ^ (srow & 7)) * 8;

  // prologue: stage tiles 0,1
  gload_lds16(kp + (size_t)srow * 64 + sc8, &sK[0][wave * 512]);
  gload_lds16(vtp + (size_t)srow * 1024 + sc8, &sV[0][wave * 512]);
  gload_lds16(kp + (size_t)(64 + srow) * 64 + sc8, &sK[1][wave * 512]);
  gload_lds16(vtp + (size_t)srow * 1024 + 64 + sc8, &sV[1][wave * 512]);

  {
    float* bf = &band[0][0][0];
    for (int i = tid; i < 8 * 16 * 20; i += 512) bf[i] = -1e30f;
  }

  bf16x8 aq[2];
#pragma unroll
  for (int kk = 0; kk < 2; ++kk)
    aq[kk] = *(const bf16x8*)&qp[(size_t)(sb + lr) * 64 + kk * 32 + lg * 8];

  f32x4 o_acc[4] = {};
  float m = -1e30f, l = 0.f;
  const int s = sb + lr;  // this lane's q row (replicated across lg groups)

  ATTN_W2                    // tile0 staged; tile1's 2 ops may be outstanding
  ATTN_TILE(0, 0, 2)  ATTN_W2
  ATTN_TILE(1, 1, 0)  ATTN_W2
  ATTN_TILE(2, 2, 1)  ATTN_W2
  ATTN_TILE(3, 0, 2)  ATTN_W2
  ATTN_TILE(4, 1, 0)  ATTN_W2
  ATTN_TILE(5, 2, 1)  ATTN_W2
  ATTN_TILE(6, 0, 2)  ATTN_W2
  ATTN_TILE(7, 1, 0)  ATTN_W2
  ATTN_TILE(8, 2, 1)  ATTN_W2
  ATTN_TILE(9, 0, 2)  ATTN_W2
  ATTN_TILE(10, 1, 0) ATTN_W2
  ATTN_TILE(11, 2, 1) ATTN_W2
  ATTN_TILE(12, 0, 2) ATTN_W2
  ATTN_TILE(13, 1, 0) ATTN_W0
  ATTN_TILE(14, 2, 1) ATTN_W0
  ATTN_TILE(15, 0, 2)

  // ---- epilogue: normalize + v_dist band correction, write (s,b,h*d) bf16 ----
  const float inv = 1.f / l;
  float psum[10];
  psum[0] = EXP2F(band[wave][lr][9] - m);
#pragma unroll
  for (int c = 1; c < 10; ++c)
    psum[c] = EXP2F(band[wave][lr][9 - c] - m) +
              EXP2F(band[wave][lr][9 + c] - m);
#pragma unroll
  for (int dj = 0; dj < 4; ++dj) {
    bf16x4 ov;
#pragma unroll
    for (int rg = 0; rg < 4; ++rg) {
      const int d = dj * 16 + lg * 4 + rg;
      float acc2 = 0.f;
#pragma unroll
      for (int c = 0; c < 10; ++c)
        acc2 += psum[c] * (vde[c * 64 + d] - vde[640 + d]);
      ov[rg] = (__bf16)((o_acc[dj][rg] + acc2) * inv + vde[640 + d]);
    }
    *(bf16x4*)&O[((size_t)(s * 8 + b)) * 1024 + h * 64 + dj * 16 + lg * 4] = ov;
  }
}

extern "C" void kernel_launch(void* const* d_in, const int* in_sizes, int n_in,
                              void* d_out, int out_size, void* d_ws, size_t ws_size,
                              hipStream_t stream) {
  (void)in_sizes; (void)n_in; (void)out_size; (void)ws_size;
  const float* inputs = (const float*)d_in[0];
  const float* W_in   = (const float*)d_in[1];
  const float* b_in   = (const float*)d_in[2];
  const float* kde    = (const float*)d_in[3];
  const float* vde    = (const float*)d_in[4];
  const float* W_out  = (const float*)d_in[5];
  const float* b_out  = (const float*)d_in[6];
  float* out = (float*)d_out;

  char* ws = (char*)d_ws;
  __bf16* qkvt  = (__bf16*)(ws);              // (3,8,16,1024,64) bf16: 50331648 B
  __bf16* vt    = (__bf16*)(ws + 50331648);   // (128,64,1024)  bf16: 16777216 B
  float*  biasD = (float*) (ws + 67108864);   // (131072,16)    f32:   8388608 B
  __bf16* Xb    = (__bf16*)(ws + 75497472);   // (8192,1024)    bf16: 16777216 B
  __bf16* Ob    = (__bf16*)(ws + 75497472);   // reuse Xb region after GEMM1
  __bf16* Wb_in = (__bf16*)(ws + 92274688);   // (3072,1024)    bf16:  6291456 B
  __bf16* Wb_out= (__bf16*)(ws + 98566144);   // (1024,1024)    bf16:  2097152 B

  f2b3_kernel<<<6144, 256, 0, stream>>>(inputs, Xb, W_in, Wb_in, W_out, Wb_out);

  // GEMM1: 64 M-bands x 24 N-tiles = 1536 blocks (1536 % 8 == 0, CPX=192)
  gemm_nt<0><<<1536, 256, 0, stream>>>(Xb, Wb_in, b_in, 1024, nullptr, qkvt, 3072, 24, 192);
  vtrans_kernel<<<2048, 256, 0, stream>>>(qkvt + (size_t)2 * 128 * 65536, vt);
  qkbias_kernel<<<8192, 256, 0, stream>>>(qkvt, kde, biasD);
  attn_kernel<<<1024, 512, 0, stream>>>(qkvt, vt, biasD, vde, Ob);
  // GEMM2: 64 x 8 = 512 blocks (CPX=64)
  gemm_nt<1><<<512, 256, 0, stream>>>(Ob, Wb_out, b_out, 1024, out, nullptr, 1024, 8, 64);
}